// Round 12
// baseline (2182.125 us; speedup 1.0000x reference)
//
#include <hip/hip_runtime.h>
#include <math.h>

// KimiK2 MoE gate. Round 12: w via async global_load_lds (double-buffered,
// XOR-swizzled via pre-swizzled source; byte-identical to r11) + x on the
// SCALAR pipe (wave-uniform s_load_dwordx4, prefetched one q-group ahead).
// Cuts DS reads from 12 to 4 per q-group -> FMA-issue-bound.
// Semantics bit-identical to round 7/9/11 (ties -> higher index).
// Output: [T*8 indices as float][T*8 weights].

#define HH 7168
#define EE 256
#define BMT 32
#define BK 32
#define NTH 256

typedef float v4f __attribute__((ext_vector_type(4)));

struct SMem {
    union {
        float wbuf[2][EE * BK];     // 64 KB (2 x 32 KB w slices)
        float logits[BMT][EE];      // 32 KB
    } u;
    float bias[EE];
};

__device__ __forceinline__ void gl16(const void* g, void* l) {
    __builtin_amdgcn_global_load_lds(
        (__attribute__((address_space(1))) const void*)g,
        (__attribute__((address_space(3))) void*)l, 16, 0, 0);
}

__global__ __launch_bounds__(NTH, 2)
void moe_gate(const float* __restrict__ x, const float* __restrict__ w,
              const float* __restrict__ bias, float* __restrict__ out, int T) {
    __shared__ SMem sm;
    const int tid = threadIdx.x;
    const int bm = blockIdx.x * BMT;
    sm.bias[tid] = bias[tid];
    const int lane = tid & 63;
    const int wv = __builtin_amdgcn_readfirstlane(tid >> 6);
    const int l3 = lane >> 3, l7 = lane & 7;

    // w staging: wave wv stages rows [wv*64, wv*64+64) (verified r11 layout)
    const int cch = l7 ^ l3;  // pre-swizzled source chunk
    const float* wsrc = w + (size_t)(wv * 64 + l3) * HH + cch * 4;
    float* const wdst0 = &sm.u.wbuf[0][wv * 64 * BK];
    float* const wdst1 = &sm.u.wbuf[1][wv * 64 * BK];

    // wave-uniform x base (8 tokens per wave) -> scalar loads
    const float* xr = x + (size_t)(bm + wv * 8) * HH;

    float acc[8][4];
    #pragma unroll
    for (int t = 0; t < 8; ++t)
        #pragma unroll
        for (int j = 0; j < 4; ++j) acc[t][j] = 0.f;

    // prologue: stage w slice 0 into buffer 0
    #pragma unroll
    for (int p = 0; p < 8; ++p)
        gl16(wsrc + (size_t)p * 8 * HH, wdst0 + p * 8 * BK);
    __syncthreads();

    // x prefetch for slice 0, q=0
    v4f xq[8], xn[8];
    #pragma unroll
    for (int t = 0; t < 8; ++t)
        xq[t] = *(const v4f*)(xr + (size_t)t * HH);

    const int NT = HH / BK; // 224
    for (int ts = 0; ts < NT; ++ts) {
        const int b = ts & 1;
        const int k0 = ts * BK;
        if (ts + 1 < NT) {
            float* wd = (b ? wdst0 : wdst1);
            #pragma unroll
            for (int p = 0; p < 8; ++p)
                gl16(wsrc + (size_t)p * 8 * HH + k0 + BK, wd + p * 8 * BK);
        }
        const float* wl = sm.u.wbuf[b];
        #pragma unroll
        for (int q = 0; q < 8; ++q) {
            const int wq = ((q ^ l7) << 2);       // swizzled k-chunk
            v4f w0 = *(const v4f*)&wl[(lane      ) * BK + wq];
            v4f w1 = *(const v4f*)&wl[(lane +  64) * BK + wq];
            v4f w2 = *(const v4f*)&wl[(lane + 128) * BK + wq];
            v4f w3 = *(const v4f*)&wl[(lane + 192) * BK + wq];
            // prefetch next q-group's x (scalar pipe, consumed next iter)
            if (q < 7) {
                #pragma unroll
                for (int t = 0; t < 8; ++t)
                    xn[t] = *(const v4f*)(xr + (size_t)t * HH + k0 + (q + 1) * 4);
            } else if (ts + 1 < NT) {
                #pragma unroll
                for (int t = 0; t < 8; ++t)
                    xn[t] = *(const v4f*)(xr + (size_t)t * HH + k0 + BK);
            }
            #pragma unroll
            for (int t = 0; t < 8; ++t) {
                #pragma unroll
                for (int c = 0; c < 4; ++c) {     // k ascends per (t,expert)
                    float xs = xq[t][c];
                    acc[t][0] = fmaf(xs, w0[c], acc[t][0]);
                    acc[t][1] = fmaf(xs, w1[c], acc[t][1]);
                    acc[t][2] = fmaf(xs, w2[c], acc[t][2]);
                    acc[t][3] = fmaf(xs, w3[c], acc[t][3]);
                }
            }
            #pragma unroll
            for (int t = 0; t < 8; ++t) xq[t] = xn[t];
        }
        __syncthreads();  // staged w landed; all waves done with buffer
    }

    // dump logits (union with wbuf: all w reads complete)
    #pragma unroll
    for (int t = 0; t < 8; ++t)
        #pragma unroll
        for (int j = 0; j < 4; ++j)
            sm.u.logits[wv * 8 + t][lane + 64 * j] = acc[t][j];
    __syncthreads();

    // ---- routing: round-7 verbatim (ties -> higher index) ----
    for (int tt = wv; tt < BMT; tt += 4) {
        const int gt = bm + tt;
        float4 lg = *(const float4*)&sm.u.logits[tt][lane * 4];
        float lgv[4] = {lg.x, lg.y, lg.z, lg.w};
        float s[4], sc[4], m[4];
        #pragma unroll
        for (int j = 0; j < 4; ++j) {
            float e = (float)exp(-(double)lgv[j]);
            float u = __fadd_rn(1.0f, e);
            s[j] = __fdiv_rn(1.0f, u);
            sc[j] = __fadd_rn(s[j], sm.bias[lane * 4 + j]);
        }
        float a1 = fmaxf(sc[0], sc[1]), a2 = fminf(sc[0], sc[1]);
        if (sc[2] > a1) { a2 = a1; a1 = sc[2]; } else a2 = fmaxf(a2, sc[2]);
        if (sc[3] > a1) { a2 = a1; a1 = sc[3]; } else a2 = fmaxf(a2, sc[3]);
        #pragma unroll
        for (int off = 1; off <= 4; off <<= 1) {
            float b1 = __shfl_xor(a1, off);
            float b2 = __shfl_xor(a2, off);
            float m1 = fmaxf(a1, b1);
            float m2 = fmaxf(fminf(a1, b1), (a1 >= b1) ? a2 : b2);
            a1 = m1; a2 = m2;
        }
        float gsc = __fadd_rn(a1, a2);
        float gsv[8];
        #pragma unroll
        for (int g = 0; g < 8; ++g) gsv[g] = __shfl(gsc, g * 8);
        int gm = lane >> 3;
        int rank = 0;
        #pragma unroll
        for (int hh = 0; hh < 8; ++hh)
            rank += (gsv[hh] > gsv[gm]) || (gsv[hh] == gsv[gm] && hh > gm);
        bool selg = rank < 4;
        #pragma unroll
        for (int j = 0; j < 4; ++j) m[j] = selg ? sc[j] : 0.0f;

        float selw = 0.f; int seli = 0;
        #pragma unroll
        for (int k = 0; k < 8; ++k) {
            float bv = m[0]; int bj = 0;
            #pragma unroll
            for (int j = 1; j < 4; ++j)
                if (m[j] >= bv) { bv = m[j]; bj = j; }
            float v = bv; int ii = lane * 4 + bj;
            #pragma unroll
            for (int off = 1; off < 64; off <<= 1) {
                float ov = __shfl_xor(v, off);
                int oi = __shfl_xor(ii, off);
                if (ov > v || (ov == v && oi > ii)) { v = ov; ii = oi; }
            }
            int oj = ii & 3, ol = ii >> 2;
            float cand = (oj == 0) ? s[0] : (oj == 1) ? s[1]
                       : (oj == 2) ? s[2] : s[3];
            float wgt = __shfl(cand, ol);
            if (lane == k) { seli = ii; selw = wgt; }
            if (lane == ol) {
                if (oj == 0) m[0] = -1e30f;
                else if (oj == 1) m[1] = -1e30f;
                else if (oj == 2) m[2] = -1e30f;
                else m[3] = -1e30f;
            }
        }
        float wk[8];
        #pragma unroll
        for (int k = 0; k < 8; ++k) wk[k] = __shfl(selw, k);
        float denom = __fadd_rn(
            __fadd_rn(__fadd_rn(wk[0], wk[1]), __fadd_rn(wk[2], wk[3])),
            __fadd_rn(__fadd_rn(wk[4], wk[5]), __fadd_rn(wk[6], wk[7])));
        denom = __fadd_rn(denom, 1e-20f);
        if (lane < 8) {
            out[(size_t)gt * 8 + lane] = (float)seli;
            out[(size_t)T * 8 + (size_t)gt * 8 + lane] =
                __fmul_rn(__fdiv_rn(selw, denom), 2.5f);
        }
    }
}

extern "C" void kernel_launch(void* const* d_in, const int* in_sizes, int n_in,
                              void* d_out, int out_size, void* d_ws, size_t ws_size,
                              hipStream_t stream) {
    const float* x    = (const float*)d_in[0];
    const float* w    = (const float*)d_in[1];
    const float* bias = (const float*)d_in[2];
    float* out = (float*)d_out;
    const int T = in_sizes[0] / HH; // 16384
    moe_gate<<<T / BMT, NTH, 0, stream>>>(x, w, bias, out, T);
}

// Round 13
// 1125.056 us; speedup vs baseline: 1.9396x; 1.9396x over previous
//
#include <hip/hip_runtime.h>
#include <math.h>

// KimiK2 MoE gate. Round 13: w via async global_load_lds (double-buffered,
// pre-swizzled source, r11-verbatim) + x per-lane in VGPRs (one v4f/slice,
// vmcnt queue) broadcast via v_readlane into FMA scalar operands.
// DS pipe = w only (4 b128/q-group). Semantics bit-identical to r7/9/11.
// Output: [T*8 indices as float][T*8 weights].

#define HH 7168
#define EE 256
#define BMT 32
#define BK 32
#define NTH 256

typedef float v4f __attribute__((ext_vector_type(4)));

struct SMem {
    union {
        float wbuf[2][EE * BK];     // 64 KB (2 x 32 KB w slices)
        float logits[BMT][EE];      // 32 KB
    } u;
    float bias[EE];
};

__device__ __forceinline__ void gl16(const void* g, void* l) {
    __builtin_amdgcn_global_load_lds(
        (__attribute__((address_space(1))) const void*)g,
        (__attribute__((address_space(3))) void*)l, 16, 0, 0);
}

__device__ __forceinline__ float rdl(float v, int l) {
    return __int_as_float(__builtin_amdgcn_readlane(__float_as_int(v), l));
}

__global__ __launch_bounds__(NTH, 2)
void moe_gate(const float* __restrict__ x, const float* __restrict__ w,
              const float* __restrict__ bias, float* __restrict__ out, int T) {
    __shared__ SMem sm;
    const int tid = threadIdx.x;
    const int bm = blockIdx.x * BMT;
    sm.bias[tid] = bias[tid];
    const int lane = tid & 63;
    const int wv = __builtin_amdgcn_readfirstlane(tid >> 6);
    const int l3 = lane >> 3, l7 = lane & 7;

    // w staging: wave wv stages rows [wv*64, wv*64+64) (r11-verified layout)
    const int cch = l7 ^ l3;  // pre-swizzled source chunk
    const float* wsrc = w + (size_t)(wv * 64 + l3) * HH + cch * 4;
    float* const wdst0 = &sm.u.wbuf[0][wv * 64 * BK];
    float* const wdst1 = &sm.u.wbuf[1][wv * 64 * BK];

    // x: lane holds token l3 (of this wave's 8), k-chunk l7 -> per-lane v4f
    const float* xsrc = x + (size_t)(bm + wv * 8 + l3) * HH + l7 * 4;

    float acc[8][4];
    #pragma unroll
    for (int t = 0; t < 8; ++t)
        #pragma unroll
        for (int j = 0; j < 4; ++j) acc[t][j] = 0.f;

    // prologue: stage w slice 0; load x slice 0
    #pragma unroll
    for (int p = 0; p < 8; ++p)
        gl16(wsrc + (size_t)p * 8 * HH, wdst0 + p * 8 * BK);
    v4f xq = *(const v4f*)xsrc;
    v4f xn = xq;
    __syncthreads();

    const int NT = HH / BK; // 224
    for (int ts = 0; ts < NT; ++ts) {
        const int b = ts & 1;
        const int k0 = ts * BK;
        if (ts + 1 < NT) {
            float* wd = (b ? wdst0 : wdst1);
            #pragma unroll
            for (int p = 0; p < 8; ++p)
                gl16(wsrc + (size_t)p * 8 * HH + k0 + BK, wd + p * 8 * BK);
            xn = *(const v4f*)(xsrc + k0 + BK);
        }
        const float* wl = sm.u.wbuf[b];
        #pragma unroll
        for (int q = 0; q < 8; ++q) {
            const int wq = ((q ^ l7) << 2);       // swizzled k-chunk
            v4f w0 = *(const v4f*)&wl[(lane      ) * BK + wq];
            v4f w1 = *(const v4f*)&wl[(lane +  64) * BK + wq];
            v4f w2 = *(const v4f*)&wl[(lane + 128) * BK + wq];
            v4f w3 = *(const v4f*)&wl[(lane + 192) * BK + wq];
            #pragma unroll
            for (int t = 0; t < 8; ++t) {
                #pragma unroll
                for (int c = 0; c < 4; ++c) {     // k ascends per (t,expert)
                    float xs = rdl(xq[c], t * 8 + q);
                    acc[t][0] = fmaf(xs, w0[c], acc[t][0]);
                    acc[t][1] = fmaf(xs, w1[c], acc[t][1]);
                    acc[t][2] = fmaf(xs, w2[c], acc[t][2]);
                    acc[t][3] = fmaf(xs, w3[c], acc[t][3]);
                }
            }
        }
        __syncthreads();  // staged w landed; all waves done with buffer
        xq = xn;
    }

    // dump logits (union with wbuf: all w reads complete)
    #pragma unroll
    for (int t = 0; t < 8; ++t)
        #pragma unroll
        for (int j = 0; j < 4; ++j)
            sm.u.logits[wv * 8 + t][lane + 64 * j] = acc[t][j];
    __syncthreads();

    // ---- routing: round-7 verbatim (ties -> higher index) ----
    for (int tt = wv; tt < BMT; tt += 4) {
        const int gt = bm + tt;
        float4 lg = *(const float4*)&sm.u.logits[tt][lane * 4];
        float lgv[4] = {lg.x, lg.y, lg.z, lg.w};
        float s[4], sc[4], m[4];
        #pragma unroll
        for (int j = 0; j < 4; ++j) {
            float e = (float)exp(-(double)lgv[j]);
            float u = __fadd_rn(1.0f, e);
            s[j] = __fdiv_rn(1.0f, u);
            sc[j] = __fadd_rn(s[j], sm.bias[lane * 4 + j]);
        }
        float a1 = fmaxf(sc[0], sc[1]), a2 = fminf(sc[0], sc[1]);
        if (sc[2] > a1) { a2 = a1; a1 = sc[2]; } else a2 = fmaxf(a2, sc[2]);
        if (sc[3] > a1) { a2 = a1; a1 = sc[3]; } else a2 = fmaxf(a2, sc[3]);
        #pragma unroll
        for (int off = 1; off <= 4; off <<= 1) {
            float b1 = __shfl_xor(a1, off);
            float b2 = __shfl_xor(a2, off);
            float m1 = fmaxf(a1, b1);
            float m2 = fmaxf(fminf(a1, b1), (a1 >= b1) ? a2 : b2);
            a1 = m1; a2 = m2;
        }
        float gsc = __fadd_rn(a1, a2);
        float gsv[8];
        #pragma unroll
        for (int g = 0; g < 8; ++g) gsv[g] = __shfl(gsc, g * 8);
        int gm = lane >> 3;
        int rank = 0;
        #pragma unroll
        for (int hh = 0; hh < 8; ++hh)
            rank += (gsv[hh] > gsv[gm]) || (gsv[hh] == gsv[gm] && hh > gm);
        bool selg = rank < 4;
        #pragma unroll
        for (int j = 0; j < 4; ++j) m[j] = selg ? sc[j] : 0.0f;

        float selw = 0.f; int seli = 0;
        #pragma unroll
        for (int k = 0; k < 8; ++k) {
            float bv = m[0]; int bj = 0;
            #pragma unroll
            for (int j = 1; j < 4; ++j)
                if (m[j] >= bv) { bv = m[j]; bj = j; }
            float v = bv; int ii = lane * 4 + bj;
            #pragma unroll
            for (int off = 1; off < 64; off <<= 1) {
                float ov = __shfl_xor(v, off);
                int oi = __shfl_xor(ii, off);
                if (ov > v || (ov == v && oi > ii)) { v = ov; ii = oi; }
            }
            int oj = ii & 3, ol = ii >> 2;
            float cand = (oj == 0) ? s[0] : (oj == 1) ? s[1]
                       : (oj == 2) ? s[2] : s[3];
            float wgt = __shfl(cand, ol);
            if (lane == k) { seli = ii; selw = wgt; }
            if (lane == ol) {
                if (oj == 0) m[0] = -1e30f;
                else if (oj == 1) m[1] = -1e30f;
                else if (oj == 2) m[2] = -1e30f;
                else m[3] = -1e30f;
            }
        }
        float wk[8];
        #pragma unroll
        for (int k = 0; k < 8; ++k) wk[k] = __shfl(selw, k);
        float denom = __fadd_rn(
            __fadd_rn(__fadd_rn(wk[0], wk[1]), __fadd_rn(wk[2], wk[3])),
            __fadd_rn(__fadd_rn(wk[4], wk[5]), __fadd_rn(wk[6], wk[7])));
        denom = __fadd_rn(denom, 1e-20f);
        if (lane < 8) {
            out[(size_t)gt * 8 + lane] = (float)seli;
            out[(size_t)T * 8 + (size_t)gt * 8 + lane] =
                __fmul_rn(__fdiv_rn(selw, denom), 2.5f);
        }
    }
}

extern "C" void kernel_launch(void* const* d_in, const int* in_sizes, int n_in,
                              void* d_out, int out_size, void* d_ws, size_t ws_size,
                              hipStream_t stream) {
    const float* x    = (const float*)d_in[0];
    const float* w    = (const float*)d_in[1];
    const float* bias = (const float*)d_in[2];
    float* out = (float*)d_out;
    const int T = in_sizes[0] / HH; // 16384
    moe_gate<<<T / BMT, NTH, 0, stream>>>(x, w, bias, out, T);
}

// Round 14
// 1073.490 us; speedup vs baseline: 2.0327x; 1.0480x over previous
//
#include <hip/hip_runtime.h>
#include <math.h>

// KimiK2 MoE gate. Round 14: balanced-pipe tile. Wave = 16 tokens x 256
// experts (NTH=128, 2 waves/block, 512 blocks = 2/CU). w AND x staged via
// async global_load_lds (double-buffered); w read per-lane b128 (r11 XOR
// swizzle), x read as wave-uniform b128 broadcasts (~5cy, DS pipe).
// DS/CU == VALU/SIMD == FMA floor. Semantics bit-identical to r7/9/11.
// Output: [T*8 indices as float][T*8 weights].

#define HH 7168
#define EE 256
#define BMT 32
#define BK 32
#define NTH 128
#define TW 16
#define NT (HH / BK)

typedef float v4f __attribute__((ext_vector_type(4)));

struct SMem {
    union {
        float wbuf[2][EE * BK];   // 64 KB (2 x 32 KB w slices)
        float logits[BMT][EE];    // 32 KB
    } u;
    float xbuf[2][BMT * BK];      // 8 KB (2 x 4 KB x slices)
    float bias[EE];
};

__device__ __forceinline__ void gl16(const void* g, void* l) {
    __builtin_amdgcn_global_load_lds(
        (__attribute__((address_space(1))) const void*)g,
        (__attribute__((address_space(3))) void*)l, 16, 0, 0);
}

#define LOADW(dst, wl, q) do { const int wq_ = (((q) ^ l7) << 2);            \
    dst[0] = *(const v4f*)&(wl)[(lane      ) * BK + wq_];                    \
    dst[1] = *(const v4f*)&(wl)[(lane +  64) * BK + wq_];                    \
    dst[2] = *(const v4f*)&(wl)[(lane + 128) * BK + wq_];                    \
    dst[3] = *(const v4f*)&(wl)[(lane + 192) * BK + wq_]; } while (0)

#define LOADX(dst, xl, q) do { _Pragma("unroll")                             \
    for (int t_ = 0; t_ < TW; ++t_)                                          \
        dst[t_] = *(const v4f*)&(xl)[t_ * BK + (q) * 4]; } while (0)

#define FMAB(xr, wr) do { _Pragma("unroll")                                  \
    for (int t_ = 0; t_ < TW; ++t_) { _Pragma("unroll")                      \
        for (int c_ = 0; c_ < 4; ++c_) {                                     \
            const float xs_ = xr[t_][c_];                                    \
            acc[t_][0] = fmaf(xs_, wr[0][c_], acc[t_][0]);                   \
            acc[t_][1] = fmaf(xs_, wr[1][c_], acc[t_][1]);                   \
            acc[t_][2] = fmaf(xs_, wr[2][c_], acc[t_][2]);                   \
            acc[t_][3] = fmaf(xs_, wr[3][c_], acc[t_][3]); } } } while (0)

__global__ __launch_bounds__(NTH, 1)
void moe_gate(const float* __restrict__ x, const float* __restrict__ w,
              const float* __restrict__ bias, float* __restrict__ out, int T) {
    __shared__ SMem sm;
    const int tid = threadIdx.x;
    const int bm = blockIdx.x * BMT;
    sm.bias[tid] = bias[tid];
    sm.bias[tid + 128] = bias[tid + 128];
    const int lane = tid & 63;
    const int wv = __builtin_amdgcn_readfirstlane(tid >> 6);
    const int l3 = (lane >> 3) & 7, l7 = lane & 7;

    // w staging: wave wv stages rows [wv*128, wv*128+128), 16 gl16/thread.
    // Swizzle invariant (r11): stored[slot] = orig[slot ^ (row&7)], row&7=l3.
    const float* wsrc = w + (size_t)(wv * 128 + l3) * HH + ((l7 ^ l3) << 2);
    float* const wdst0 = &sm.u.wbuf[0][wv * 128 * BK];
    float* const wdst1 = &sm.u.wbuf[1][wv * 128 * BK];

    // x staging: slot s = tid + i*128 -> token s>>3, chunk l7; 2 gl16/thread
    const int tok0 = tid >> 3;
    const float* xsrc0 = x + (size_t)(bm + tok0) * HH + (l7 << 2);
    const float* xsrc1 = xsrc0 + (size_t)16 * HH;
    float* const xd00 = &sm.xbuf[0][wv * 256];
    float* const xd01 = &sm.xbuf[0][wv * 256 + 512];
    float* const xd10 = &sm.xbuf[1][wv * 256];
    float* const xd11 = &sm.xbuf[1][wv * 256 + 512];

    float acc[TW][4];
    #pragma unroll
    for (int t = 0; t < TW; ++t)
        #pragma unroll
        for (int j = 0; j < 4; ++j) acc[t][j] = 0.f;

    // prologue: stage slice 0 into buffer 0
    #pragma unroll
    for (int p = 0; p < 16; ++p)
        gl16(wsrc + (size_t)p * 8 * HH, wdst0 + p * 8 * BK);
    gl16(xsrc0, xd00);
    gl16(xsrc1, xd01);
    __syncthreads();

    for (int ts = 0; ts < NT; ++ts) {
        const int b = ts & 1;
        if (ts + 1 < NT) {
            const int k1 = (ts + 1) * BK;
            float* wd = b ? wdst0 : wdst1;
            #pragma unroll
            for (int p = 0; p < 16; ++p)
                gl16(wsrc + (size_t)p * 8 * HH + k1, wd + p * 8 * BK);
            gl16(xsrc0 + k1, b ? xd00 : xd10);
            gl16(xsrc1 + k1, b ? xd01 : xd11);
        }
        const float* wl = b ? sm.u.wbuf[1] : sm.u.wbuf[0];
        const float* xl = (b ? &sm.xbuf[1][0] : &sm.xbuf[0][0]) + wv * 512;

        v4f wA[4], wB[4], xA[TW], xB[TW];
        LOADW(wA, wl, 0); LOADX(xA, xl, 0);
        LOADW(wB, wl, 1); LOADX(xB, xl, 1); FMAB(xA, wA);   // q=0
        LOADW(wA, wl, 2); LOADX(xA, xl, 2); FMAB(xB, wB);   // q=1
        LOADW(wB, wl, 3); LOADX(xB, xl, 3); FMAB(xA, wA);   // q=2
        LOADW(wA, wl, 4); LOADX(xA, xl, 4); FMAB(xB, wB);   // q=3
        LOADW(wB, wl, 5); LOADX(xB, xl, 5); FMAB(xA, wA);   // q=4
        LOADW(wA, wl, 6); LOADX(xA, xl, 6); FMAB(xB, wB);   // q=5
        LOADW(wB, wl, 7); LOADX(xB, xl, 7); FMAB(xA, wA);   // q=6
        FMAB(xB, wB);                                        // q=7
        __syncthreads();   // staged slice landed; all waves done with buffer
    }

    // dump logits (aliases wbuf[0]; all w reads complete)
    #pragma unroll
    for (int t = 0; t < TW; ++t)
        #pragma unroll
        for (int j = 0; j < 4; ++j)
            sm.u.logits[wv * TW + t][lane + 64 * j] = acc[t][j];
    __syncthreads();

    // ---- routing: round-7 verbatim (ties -> higher index) ----
    for (int tt = wv; tt < BMT; tt += 2) {
        const int gt = bm + tt;
        float4 lg = *(const float4*)&sm.u.logits[tt][lane * 4];
        float lgv[4] = {lg.x, lg.y, lg.z, lg.w};
        float s[4], sc[4], m[4];
        #pragma unroll
        for (int j = 0; j < 4; ++j) {
            float e = (float)exp(-(double)lgv[j]);
            float u = __fadd_rn(1.0f, e);
            s[j] = __fdiv_rn(1.0f, u);
            sc[j] = __fadd_rn(s[j], sm.bias[lane * 4 + j]);
        }
        float a1 = fmaxf(sc[0], sc[1]), a2 = fminf(sc[0], sc[1]);
        if (sc[2] > a1) { a2 = a1; a1 = sc[2]; } else a2 = fmaxf(a2, sc[2]);
        if (sc[3] > a1) { a2 = a1; a1 = sc[3]; } else a2 = fmaxf(a2, sc[3]);
        #pragma unroll
        for (int off = 1; off <= 4; off <<= 1) {
            float b1 = __shfl_xor(a1, off);
            float b2 = __shfl_xor(a2, off);
            float m1 = fmaxf(a1, b1);
            float m2 = fmaxf(fminf(a1, b1), (a1 >= b1) ? a2 : b2);
            a1 = m1; a2 = m2;
        }
        float gsc = __fadd_rn(a1, a2);
        float gsv[8];
        #pragma unroll
        for (int g = 0; g < 8; ++g) gsv[g] = __shfl(gsc, g * 8);
        int gm = lane >> 3;
        int rank = 0;
        #pragma unroll
        for (int hh = 0; hh < 8; ++hh)
            rank += (gsv[hh] > gsv[gm]) || (gsv[hh] == gsv[gm] && hh > gm);
        bool selg = rank < 4;
        #pragma unroll
        for (int j = 0; j < 4; ++j) m[j] = selg ? sc[j] : 0.0f;

        float selw = 0.f; int seli = 0;
        #pragma unroll
        for (int k = 0; k < 8; ++k) {
            float bv = m[0]; int bj = 0;
            #pragma unroll
            for (int j = 1; j < 4; ++j)
                if (m[j] >= bv) { bv = m[j]; bj = j; }
            float v = bv; int ii = lane * 4 + bj;
            #pragma unroll
            for (int off = 1; off < 64; off <<= 1) {
                float ov = __shfl_xor(v, off);
                int oi = __shfl_xor(ii, off);
                if (ov > v || (ov == v && oi > ii)) { v = ov; ii = oi; }
            }
            int oj = ii & 3, ol = ii >> 2;
            float cand = (oj == 0) ? s[0] : (oj == 1) ? s[1]
                       : (oj == 2) ? s[2] : s[3];
            float wgt = __shfl(cand, ol);
            if (lane == k) { seli = ii; selw = wgt; }
            if (lane == ol) {
                if (oj == 0) m[0] = -1e30f;
                else if (oj == 1) m[1] = -1e30f;
                else if (oj == 2) m[2] = -1e30f;
                else m[3] = -1e30f;
            }
        }
        float wk[8];
        #pragma unroll
        for (int k = 0; k < 8; ++k) wk[k] = __shfl(selw, k);
        float denom = __fadd_rn(
            __fadd_rn(__fadd_rn(wk[0], wk[1]), __fadd_rn(wk[2], wk[3])),
            __fadd_rn(__fadd_rn(wk[4], wk[5]), __fadd_rn(wk[6], wk[7])));
        denom = __fadd_rn(denom, 1e-20f);
        if (lane < 8) {
            out[(size_t)gt * 8 + lane] = (float)seli;
            out[(size_t)T * 8 + (size_t)gt * 8 + lane] =
                __fmul_rn(__fdiv_rn(selw, denom), 2.5f);
        }
    }
}

extern "C" void kernel_launch(void* const* d_in, const int* in_sizes, int n_in,
                              void* d_out, int out_size, void* d_ws, size_t ws_size,
                              hipStream_t stream) {
    const float* x    = (const float*)d_in[0];
    const float* w    = (const float*)d_in[1];
    const float* bias = (const float*)d_in[2];
    float* out = (float*)d_out;
    const int T = in_sizes[0] / HH; // 16384
    moe_gate<<<T / BMT, NTH, 0, stream>>>(x, w, bias, out, T);
}